// Round 2
// baseline (143.121 us; speedup 1.0000x reference)
//
#include <hip/hip_runtime.h>

typedef unsigned short ushort_t;
typedef ushort_t u16x8 __attribute__((ext_vector_type(8)));
typedef __bf16 bf16x8 __attribute__((ext_vector_type(8)));
typedef float f32x4 __attribute__((ext_vector_type(4)));

#define DET 736
#define NPAD 768
#define NT 23   // K-steps: 736 / 32

__device__ __forceinline__ ushort_t f2bf(float f) {
    unsigned u = __builtin_bit_cast(unsigned, f);
    u += 0x7FFFu + ((u >> 16) & 1u);
    return (ushort_t)(u >> 16);
}

// async global->LDS, 16B per lane. Dest must be wave-uniform base + lane*16.
__device__ __forceinline__ void gload16(const void* g, void* l) {
    __builtin_amdgcn_global_load_lds(
        (const __attribute__((address_space(1))) unsigned int*)g,
        (__attribute__((address_space(3))) unsigned int*)l,
        16, 0, 0);
}

// X[m][k] = sino[m][k] * 0.05*cos((k-367.5)*1e-3), cast to bf16
__global__ void prep_x(const float* __restrict__ sino, ushort_t* __restrict__ X, int total) {
    int idx = (blockIdx.x * blockDim.x + threadIdx.x) * 4;
    if (idx >= total) return;
    const float4 v = *(const float4*)(sino + idx);
    float vv[4] = {v.x, v.y, v.z, v.w};
    int j = idx % DET;  // 736 % 4 == 0, so 4-groups never straddle rows
    ushort_t oo[4];
#pragma unroll
    for (int t = 0; t < 4; ++t) {
        float w = 0.05f * cosf(((float)(j + t) - 367.5f) * 0.001f);
        oo[t] = f2bf(vv[t] * w);
    }
    ushort4 o; o.x = oo[0]; o.y = oo[1]; o.z = oo[2]; o.w = oo[3];
    *(ushort4*)(X + idx) = o;
}

// Bt[n][k] = f[k - n + 735]  (W symmetric => this is both W and W^T), rows n>=736 zero
__global__ void prep_bt(const float* __restrict__ filt, ushort_t* __restrict__ Bt) {
    int idx = blockIdx.x * blockDim.x + threadIdx.x;
    if (idx >= NPAD * DET) return;
    int n = idx / DET;
    int k = idx - n * DET;
    float v = (n < DET) ? filt[k - n + (DET - 1)] : 0.0f;  // index always in [0,1471)
    Bt[idx] = f2bf(v);
}

// OUT[M x 736] = X[M x 736] * W[736 x 736], bf16 MFMA, 128x128 tile, BK=32
// 2-phase double-buffered pipeline: stage tile t+1 (global_load_lds) BEFORE
// computing tile t; single __syncthreads per iter (its vmcnt(0) drain is the
// required wait for the prefetched tile). Stage latency hides under MFMA.
__global__ __launch_bounds__(256) void gemm_bt(
    const ushort_t* __restrict__ A,   // M x DET bf16 bits
    const ushort_t* __restrict__ Bt,  // NPAD x DET bf16 bits
    float* __restrict__ C, int M)
{
    __shared__ ushort_t As[2][128 * 32];
    __shared__ ushort_t Bs[2][128 * 32];

    const int tid  = threadIdx.x;
    const int lane = tid & 63;
    const int warp = tid >> 6;   // 0..3
    const int wm   = warp & 1;   // 2x2 wave grid
    const int wn   = warp >> 1;
    const int quad = lane >> 4;  // 0..3
    const int l16  = lane & 15;

    const size_t row_a0 = (size_t)blockIdx.x * 128;
    const int    row_b0 = blockIdx.y * 128;

    f32x4 acc[4][4];
#pragma unroll
    for (int i = 0; i < 4; ++i)
#pragma unroll
        for (int jx = 0; jx < 4; ++jx)
            acc[i][jx] = (f32x4){0.f, 0.f, 0.f, 0.f};

    // staging: tile = 128 rows x 32 k = 512 chunks of 16B; 256 threads x 2 chunks
    // chunk c -> LDS byte offset c*16 = (wave-uniform base) + lane*16  [gload_lds OK]
    const int c0 = tid, c1 = tid + 256;
    const int r0 = c0 >> 2, q0 = c0 & 3;
    const int r1 = c1 >> 2, q1 = c1 & 3;

    const ushort_t* gA0 = A + (row_a0 + r0) * DET + q0 * 8;
    const ushort_t* gA1 = A + (row_a0 + r1) * DET + q1 * 8;
    const ushort_t* gB0 = Bt + (size_t)(row_b0 + r0) * DET + q0 * 8;
    const ushort_t* gB1 = Bt + (size_t)(row_b0 + r1) * DET + q1 * 8;

    // prologue: stage tile 0 into buf 0, drain, sync
    gload16(gA0, As[0] + c0 * 8);
    gload16(gA1, As[0] + c1 * 8);
    gload16(gB0, Bs[0] + c0 * 8);
    gload16(gB1, Bs[0] + c1 * 8);
    __syncthreads();   // implicit vmcnt(0): tile 0 visible

    int cur = 0;
    for (int t = 0; t < NT; ++t) {
        // issue prefetch of tile t+1 into the other buffer (overlaps with compute)
        if (t + 1 < NT) {
            const int kn = (t + 1) * 32;
            gload16(gA0 + kn, As[cur ^ 1] + c0 * 8);
            gload16(gA1 + kn, As[cur ^ 1] + c1 * 8);
            gload16(gB0 + kn, Bs[cur ^ 1] + c0 * 8);
            gload16(gB1 + kn, Bs[cur ^ 1] + c1 * 8);
        }

        // compute tile t from buf[cur]
        const ushort_t* Asc = As[cur];
        const ushort_t* Bsc = Bs[cur];
        u16x8 af[4], bfr[4];
#pragma unroll
        for (int mi = 0; mi < 4; ++mi)
            af[mi] = *(const u16x8*)(Asc + (wm * 64 + mi * 16 + l16) * 32 + quad * 8);
#pragma unroll
        for (int ni = 0; ni < 4; ++ni)
            bfr[ni] = *(const u16x8*)(Bsc + (wn * 64 + ni * 16 + l16) * 32 + quad * 8);
#pragma unroll
        for (int mi = 0; mi < 4; ++mi)
#pragma unroll
            for (int ni = 0; ni < 4; ++ni)
                acc[mi][ni] = __builtin_amdgcn_mfma_f32_16x16x32_bf16(
                    __builtin_bit_cast(bf16x8, af[mi]),
                    __builtin_bit_cast(bf16x8, bfr[ni]),
                    acc[mi][ni], 0, 0, 0);

        // one barrier per iter: drains prefetch (vmcnt(0)) + guards buffer reuse
        __syncthreads();
        cur ^= 1;
    }

    // epilogue: C/D layout col=lane&15, row=quad*4+reg [verified mapping]
#pragma unroll
    for (int mi = 0; mi < 4; ++mi) {
#pragma unroll
        for (int ni = 0; ni < 4; ++ni) {
            int colg = row_b0 + wn * 64 + ni * 16 + l16;
            if (colg < DET) {
#pragma unroll
                for (int r = 0; r < 4; ++r) {
                    size_t rowg = row_a0 + wm * 64 + mi * 16 + quad * 4 + r;
                    C[rowg * DET + colg] = acc[mi][ni][r];
                }
            }
        }
    }
}

extern "C" void kernel_launch(void* const* d_in, const int* in_sizes, int n_in,
                              void* d_out, int out_size, void* d_ws, size_t ws_size,
                              hipStream_t stream) {
    const float* sino = (const float*)d_in[0];
    const float* filt = (const float*)d_in[1];
    int total = in_sizes[0];     // 16*1*1152*736 = 13,565,952
    int M = total / DET;         // 18432

    ushort_t* Xbf = (ushort_t*)d_ws;
    ushort_t* Btb = Xbf + (size_t)total;   // +27.1 MB (16B-aligned)
    float* out = (float*)d_out;

    prep_x<<<(total / 4 + 255) / 256, 256, 0, stream>>>(sino, Xbf, total);
    prep_bt<<<(NPAD * DET + 255) / 256, 256, 0, stream>>>(filt, Btb);

    dim3 grid(M / 128, NPAD / 128);  // 144 x 6
    gemm_bt<<<grid, 256, 0, stream>>>(Xbf, Btb, out, M);
}

// Round 3
// 132.183 us; speedup vs baseline: 1.0828x; 1.0828x over previous
//
#include <hip/hip_runtime.h>

typedef unsigned short ushort_t;
typedef ushort_t u16x8 __attribute__((ext_vector_type(8)));
typedef __bf16 bf16x8 __attribute__((ext_vector_type(8)));
typedef float f32x4 __attribute__((ext_vector_type(4)));

#define DET 736
#define NPAD 768
#define NT 23   // K-steps: 736 / 32

__device__ __forceinline__ ushort_t f2bf(float f) {
    unsigned u = __builtin_bit_cast(unsigned, f);
    u += 0x7FFFu + ((u >> 16) & 1u);
    return (ushort_t)(u >> 16);
}

// async global->LDS, 16B per lane. Dest must be wave-uniform base + lane*16.
__device__ __forceinline__ void gload16(const void* g, void* l) {
    __builtin_amdgcn_global_load_lds(
        (const __attribute__((address_space(1))) unsigned int*)g,
        (__attribute__((address_space(3))) unsigned int*)l,
        16, 0, 0);
}

// Bt[n][k] = w[k] * f[k - n + 735]   (cosine pre-weight folded into the filter
// matrix: OUT = (X . w) * W  ==  X * (diag(w) W)).  Rows n>=736 are zero pad.
__global__ void prep_bt(const float* __restrict__ filt, ushort_t* __restrict__ Bt) {
    int idx = blockIdx.x * blockDim.x + threadIdx.x;
    if (idx >= NPAD * DET) return;
    int n = idx / DET;
    int k = idx - n * DET;
    float w = 0.05f * cosf(((float)k - 367.5f) * 0.001f);
    float v = (n < DET) ? filt[k - n + (DET - 1)] * w : 0.0f;  // index in [0,1471)
    Bt[idx] = f2bf(v);
}

// OUT[M x 736] = sino[M x 736] * W'[736 x 736]
// A: raw fp32 sinogram, converted to bf16 during reg-staging (prep_x eliminated).
// B: bf16 weight-folded Toeplitz, staged via global_load_lds.
// Single-buffer, 2 barriers/iter; next A-tile fp32 loads issued after barrier so
// their latency hides under the MFMA compute (T14-lite).
__global__ __launch_bounds__(256, 4) void gemm_fused(
    const float* __restrict__ A,      // M x DET fp32 sinogram
    const ushort_t* __restrict__ Bt,  // NPAD x DET bf16 bits
    float* __restrict__ C, int M)
{
    __shared__ ushort_t As[128 * 32];
    __shared__ ushort_t Bs[128 * 32];

    const int tid  = threadIdx.x;
    const int lane = tid & 63;
    const int warp = tid >> 6;   // 0..3
    const int wm   = warp & 1;   // 2x2 wave grid
    const int wn   = warp >> 1;
    const int quad = lane >> 4;  // 0..3
    const int l16  = lane & 15;

    const size_t row_a0 = (size_t)blockIdx.x * 128;
    const int    row_b0 = blockIdx.y * 128;

    f32x4 acc[4][4];
#pragma unroll
    for (int i = 0; i < 4; ++i)
#pragma unroll
        for (int jx = 0; jx < 4; ++jx)
            acc[i][jx] = (f32x4){0.f, 0.f, 0.f, 0.f};

    // tile = 128 rows x 32 k; bf16 tile = 512 chunks of 16B; 256 thr x 2 chunks
    const int c0 = tid, c1 = tid + 256;
    const int r0 = c0 >> 2, q0 = c0 & 3;
    const int r1 = c1 >> 2, q1 = c1 & 3;

    const float*    gA0 = A + (row_a0 + r0) * DET + q0 * 8;   // 8 fp32 per chunk
    const float*    gA1 = A + (row_a0 + r1) * DET + q1 * 8;
    const ushort_t* gB0 = Bt + (size_t)(row_b0 + r0) * DET + q0 * 8;
    const ushort_t* gB1 = Bt + (size_t)(row_b0 + r1) * DET + q1 * 8;

    // prologue: issue A fp32 loads for tile 0
    f32x4 a0lo = *(const f32x4*)(gA0);
    f32x4 a0hi = *(const f32x4*)(gA0 + 4);
    f32x4 a1lo = *(const f32x4*)(gA1);
    f32x4 a1hi = *(const f32x4*)(gA1 + 4);

    for (int t = 0; t < NT; ++t) {
        __syncthreads();   // LDS free (previous compute done)

        // convert + write A tile (regs loaded last iter, latency already hidden)
        u16x8 oa0, oa1;
#pragma unroll
        for (int e = 0; e < 4; ++e) {
            oa0[e]     = f2bf(a0lo[e]);
            oa0[e + 4] = f2bf(a0hi[e]);
            oa1[e]     = f2bf(a1lo[e]);
            oa1[e + 4] = f2bf(a1hi[e]);
        }
        *(u16x8*)(As + c0 * 8) = oa0;
        *(u16x8*)(As + c1 * 8) = oa1;

        // stage B tile via async DMA
        const int k0 = t * 32;
        gload16(gB0 + k0, Bs + c0 * 8);
        gload16(gB1 + k0, Bs + c1 * 8);

        __syncthreads();   // drains vmcnt/lgkm: As + Bs visible

        // issue next A-tile fp32 loads; latency hides under the MFMAs below
        if (t + 1 < NT) {
            const int kn = (t + 1) * 32;
            a0lo = *(const f32x4*)(gA0 + kn);
            a0hi = *(const f32x4*)(gA0 + kn + 4);
            a1lo = *(const f32x4*)(gA1 + kn);
            a1hi = *(const f32x4*)(gA1 + kn + 4);
        }

        u16x8 af[4], bfr[4];
#pragma unroll
        for (int mi = 0; mi < 4; ++mi)
            af[mi] = *(const u16x8*)(As + (wm * 64 + mi * 16 + l16) * 32 + quad * 8);
#pragma unroll
        for (int ni = 0; ni < 4; ++ni)
            bfr[ni] = *(const u16x8*)(Bs + (wn * 64 + ni * 16 + l16) * 32 + quad * 8);
#pragma unroll
        for (int mi = 0; mi < 4; ++mi)
#pragma unroll
            for (int ni = 0; ni < 4; ++ni)
                acc[mi][ni] = __builtin_amdgcn_mfma_f32_16x16x32_bf16(
                    __builtin_bit_cast(bf16x8, af[mi]),
                    __builtin_bit_cast(bf16x8, bfr[ni]),
                    acc[mi][ni], 0, 0, 0);
    }

    // epilogue: C/D layout col=lane&15, row=quad*4+reg [verified mapping]
#pragma unroll
    for (int mi = 0; mi < 4; ++mi) {
#pragma unroll
        for (int ni = 0; ni < 4; ++ni) {
            int colg = row_b0 + wn * 64 + ni * 16 + l16;
            if (colg < DET) {
#pragma unroll
                for (int r = 0; r < 4; ++r) {
                    size_t rowg = row_a0 + wm * 64 + mi * 16 + quad * 4 + r;
                    C[rowg * DET + colg] = acc[mi][ni][r];
                }
            }
        }
    }
}

extern "C" void kernel_launch(void* const* d_in, const int* in_sizes, int n_in,
                              void* d_out, int out_size, void* d_ws, size_t ws_size,
                              hipStream_t stream) {
    const float* sino = (const float*)d_in[0];
    const float* filt = (const float*)d_in[1];
    int total = in_sizes[0];     // 16*1*1152*736 = 13,565,952
    int M = total / DET;         // 18432

    ushort_t* Btb = (ushort_t*)d_ws;   // 768*736*2 = 1.08 MB
    float* out = (float*)d_out;

    prep_bt<<<(NPAD * DET + 255) / 256, 256, 0, stream>>>(filt, Btb);

    dim3 grid(M / 128, NPAD / 128);  // 144 x 6
    gemm_fused<<<grid, 256, 0, stream>>>(sino, Btb, out, M);
}